// Round 5
// baseline (357.784 us; speedup 1.0000x reference)
//
#include <hip/hip_runtime.h>

#define B_DIM   512
#define IN_DIM  65536
#define OUT_DIM 16384
#define K_DIM   32

static __device__ __forceinline__ unsigned short f2bf(float f) {
    unsigned u = __builtin_bit_cast(unsigned, f);
    return (unsigned short)((u + 0x7FFFu + ((u >> 16) & 1u)) >> 16);   // RNE
}

// ---------------------------------------------------------------------------
// Kernel 1: transpose + fp32->bf16. R1's proven structure (64x64 tile,
// stride-65 LDS => 2-way max conflicts in BOTH phases), ushort4 output.
// Traffic: 128 MiB read + 64 MiB write.
// ---------------------------------------------------------------------------
#define TT 64
__global__ __launch_bounds__(256) void transpose_bf16_k(const float* __restrict__ x,
                                                        unsigned short* __restrict__ xT) {
    __shared__ float tile[TT][TT + 1];
    const int c0 = blockIdx.x * TT;   // in-col base (= xT row base)
    const int r0 = blockIdx.y * TT;   // b base     (= xT col base)
    const int t  = threadIdx.x;
    const int cq = (t & 15) * 4;
    const int r  = t >> 4;

    #pragma unroll
    for (int rr = 0; rr < TT; rr += 16) {
        float4 v = *(const float4*)(x + (size_t)(r0 + r + rr) * IN_DIM + c0 + cq);
        tile[cq + 0][r + rr] = v.x;    // stride-65 rows: 2-way max (free)
        tile[cq + 1][r + rr] = v.y;
        tile[cq + 2][r + rr] = v.z;
        tile[cq + 3][r + rr] = v.w;
    }
    __syncthreads();

    const int rq = (t & 15) * 4;      // b-quad
    const int c  = t >> 4;
    #pragma unroll
    for (int cc = 0; cc < TT; cc += 16) {
        ushort4 p;
        p.x = f2bf(tile[c + cc][rq + 0]);   // 2-way max
        p.y = f2bf(tile[c + cc][rq + 1]);
        p.z = f2bf(tile[c + cc][rq + 2]);
        p.w = f2bf(tile[c + cc][rq + 3]);
        *(ushort4*)(xT + (size_t)(c0 + c + cc) * B_DIM + r0 + rq) = p;
    }
}

// ---------------------------------------------------------------------------
// Kernel 2: main gather. Block = 256 threads (4 waves), 8 outputs x 512 b.
// Waves 0-1: o 0..3 / b-halves; waves 2-3: o 4..7 / b-halves. Grid 2048 ->
// 8 blocks/CU x 4 waves = 32 waves/CU (occupancy-max at 64 VGPR).
// Each wave preloads its 4ox32k idx/w tile as int2/float2 per lane, then
// broadcasts via readlane: 128 fully-unrolled independent 512 B gathers.
// Epilogue corner-turns through LDS (2-way max) for coalesced out writes.
// ---------------------------------------------------------------------------
#define SE 520

static __device__ __forceinline__ float rl_f(float a, float b, int flat) {
    return __int_as_float(__builtin_amdgcn_readlane(
        __float_as_int((flat & 1) ? b : a), flat >> 1));
}
static __device__ __forceinline__ int rl_i(int a, int b, int flat) {
    return __builtin_amdgcn_readlane((flat & 1) ? b : a, flat >> 1);
}

__global__ __launch_bounds__(256, 8) void sparse_main(const unsigned short* __restrict__ xT,
                                                      const int*   __restrict__ idxp,
                                                      const float* __restrict__ wp,
                                                      const float* __restrict__ biasp,
                                                      float*       __restrict__ out) {
    __shared__ float lds[8][SE];
    const int o_blk = blockIdx.x * 8;
    const int t     = threadIdx.x;
    const int lane  = t & 63;
    const int o_grp = (t >> 7) * 4;        // waves 0-1 -> 0, waves 2-3 -> 4
    const int b4    = (t & 127) * 4;       // this thread's 4 b's

    // wave's idx/w tile: 4 o x 32 k = 128 elems = 64 lanes x {int2,float2}
    const int2   iv = ((const int2*)  (idxp + (o_blk + o_grp) * K_DIM))[lane];
    const float2 wv = ((const float2*)(wp   + (o_blk + o_grp) * K_DIM))[lane];

    float4 acc[4];
    #pragma unroll
    for (int o = 0; o < 4; ++o) acc[o] = make_float4(0.f, 0.f, 0.f, 0.f);

    #pragma unroll
    for (int o = 0; o < 4; ++o) {
        #pragma unroll
        for (int k = 0; k < K_DIM; ++k) {
            const int   flat = o * K_DIM + k;            // compile-time const
            const int   sidx = rl_i(iv.x, iv.y, flat);
            const float sw   = rl_f(wv.x, wv.y, flat);
            const uint2 u = *(const uint2*)(xT + ((size_t)sidx << 9) + b4);
            acc[o].x = fmaf(sw, __uint_as_float(u.x << 16),         acc[o].x);
            acc[o].y = fmaf(sw, __uint_as_float(u.x & 0xFFFF0000u), acc[o].y);
            acc[o].z = fmaf(sw, __uint_as_float(u.y << 16),         acc[o].z);
            acc[o].w = fmaf(sw, __uint_as_float(u.y & 0xFFFF0000u), acc[o].w);
        }
    }

    #pragma unroll
    for (int o = 0; o < 4; ++o) {
        const float bv = biasp[o_blk + o_grp + o];
        acc[o].x += bv; acc[o].y += bv; acc[o].z += bv; acc[o].w += bv;
        *(float4*)(&lds[o_grp + o][b4]) = acc[o];
    }
    __syncthreads();

    // corner-turn write: 512 b x 8 o = 4096 floats, 4 passes of 1024
    #pragma unroll
    for (int p = 0; p < 4; ++p) {
        const int q = p * 1024 + t * 4;
        const int b = q >> 3;
        const int o = q & 7;               // 0 or 4
        float4 v;
        v.x = lds[o + 0][b];               // 2-way max (o=0 vs o=4 same bank)
        v.y = lds[o + 1][b];
        v.z = lds[o + 2][b];
        v.w = lds[o + 3][b];
        *(float4*)(out + (size_t)b * OUT_DIM + o_blk + o) = v;
    }
}

// ---------------------------------------------------------------------------
// Fallback (workspace too small): direct gather, correct but slow.
// ---------------------------------------------------------------------------
__global__ void sparse_fallback(const float* __restrict__ x,
                                const int*   __restrict__ idxp,
                                const float* __restrict__ wp,
                                const float* __restrict__ biasp,
                                float*       __restrict__ out) {
    const int i = blockIdx.x * blockDim.x + threadIdx.x;
    if (i >= B_DIM * OUT_DIM) return;
    const int b = i / OUT_DIM;
    const int o = i % OUT_DIM;
    float a = biasp[o];
    for (int k = 0; k < K_DIM; ++k) {
        const int idx = idxp[o * K_DIM + k];
        a = fmaf(wp[o * K_DIM + k], x[(size_t)b * IN_DIM + idx], a);
    }
    out[i] = a;
}

extern "C" void kernel_launch(void* const* d_in, const int* in_sizes, int n_in,
                              void* d_out, int out_size, void* d_ws, size_t ws_size,
                              hipStream_t stream) {
    const float* x       = (const float*)d_in[0];
    const int*   indices = (const int*)  d_in[1];
    const float* weight  = (const float*)d_in[2];
    const float* bias    = (const float*)d_in[3];
    float*       out     = (float*)d_out;

    const size_t need = (size_t)IN_DIM * B_DIM * sizeof(unsigned short);  // 64 MiB
    if (ws_size >= need) {
        unsigned short* xT = (unsigned short*)d_ws;
        dim3 tgrid(IN_DIM / TT, B_DIM / TT);   // (1024, 8)
        transpose_bf16_k<<<tgrid, 256, 0, stream>>>(x, xT);
        sparse_main<<<OUT_DIM / 8, 256, 0, stream>>>(xT, indices, weight, bias, out);
    } else {
        const int n = B_DIM * OUT_DIM;
        sparse_fallback<<<(n + 255) / 256, 256, 0, stream>>>(x, indices, weight, bias, out);
    }
}